// Round 4
// baseline (290.171 us; speedup 1.0000x reference)
//
#include <hip/hip_runtime.h>
#include <stdint.h>

typedef __bf16 bf16_t;
typedef __bf16 bf16x4 __attribute__((ext_vector_type(4)));
typedef __bf16 bf16x8 __attribute__((ext_vector_type(8)));
typedef float  f32x4  __attribute__((ext_vector_type(4)));

#define BB   4
#define SS   2048
#define DD   1024
#define HH   16
#define DH   64

#if __has_builtin(__builtin_amdgcn_exp2f)
#define EXP2F(x) __builtin_amdgcn_exp2f(x)
#else
#define EXP2F(x) __expf((x) * 0.6931471805599453f)
#endif

// Q pre-scale: 0.125 * log2(e). Folded into Qb at the GEMM1 epilogue (f32
// multiply BEFORE bf16 round -> zero precision cost, bf16 rounding is
// scale-invariant). Softmax is invariant to a constant factor on p, so the
// old -8 bias is dropped entirely; attn inner loop does p = exp2(s) raw.
#define QSC 0.18033688011112042f

// ---------------------------------------------------------------- helpers
__device__ __forceinline__ void gload_lds16(const void* g, void* l) {
    // dest LDS addr = wave-uniform base + lane*16 (measured m104/m108)
    __builtin_amdgcn_global_load_lds(
        (__attribute__((address_space(1))) void*)(uintptr_t)g,
        (__attribute__((address_space(3))) void*)(uint32_t)(uintptr_t)l,
        16, 0, 0);
}

// ---------------------------------------------------------------- fused prep
// one launch: X fp32->bf16 (8192 blocks), 4 weights fp32->bf16 (4096),
// rope cos/sin table (4096), bias pack (12). grid = 16396.
// R12: rope table layout is now [pr][s] (pr-major) so the GEMM1 epilogue's
// 4 consecutive-s entries per (i,j) are one 32B contiguous load, and a
// wave's accesses collapse to 8x128B segments instead of 32 scattered lines.
__global__ __launch_bounds__(256) void prep_kernel(
        const float* __restrict__ queries,
        const float* __restrict__ Wq, const float* __restrict__ Wk,
        const float* __restrict__ Wv, const float* __restrict__ Wo,
        const float* __restrict__ bq, const float* __restrict__ bk,
        const float* __restrict__ bv,
        bf16_t* __restrict__ Xb, bf16_t* __restrict__ Wqkv,
        bf16_t* __restrict__ Wob, float* __restrict__ bqkv,
        float2* __restrict__ tab)
{
    const int bid = blockIdx.x, t = threadIdx.x;
    if (bid < 8192) {                       // X convert: 2097152 float4
        const int i = bid * 256 + t;
        float4 v = ((const float4*)queries)[i];
        bf16x4 o;
        o.x = (bf16_t)v.x; o.y = (bf16_t)v.y; o.z = (bf16_t)v.z; o.w = (bf16_t)v.w;
        ((bf16x4*)Xb)[i] = o;
    } else if (bid < 12288) {               // weights: 1048576 float4
        const int i = (bid - 8192) * 256 + t;
        const int which = i >> 18, p = i & 262143;
        const float* src = (which == 0) ? Wq : (which == 1) ? Wk : (which == 2) ? Wv : Wo;
        bf16_t* dst = (which < 3) ? (Wqkv + (long)which * 1048576) : Wob;
        float4 v = ((const float4*)src)[p];
        bf16x4 o;
        o.x = (bf16_t)v.x; o.y = (bf16_t)v.y; o.z = (bf16_t)v.z; o.w = (bf16_t)v.w;
        ((bf16x4*)dst)[p] = o;
    } else if (bid < 16384) {               // rope table: [pr][s], 512*2048
        const int i = (bid - 12288) * 256 + t;
        const int pr = i >> 11, s = i & 2047;   // pr wave-uniform per block
        // 10000^(-2pr/1024) = exp2(-2pr * log2(10000)/1024); exp2f is HW-fast
        float inv = exp2f(-(float)(2 * pr) * 0.012976281620653759f);
        float c, sn;
        sincosf((float)s * inv, &sn, &c);
        tab[i] = make_float2(c, sn);        // tab[pr*2048 + s]
    } else {                                // bias pack: 3072
        const int i = (bid - 16384) * 256 + t;
        if (i < 3072)
            bqkv[i] = (i < 1024) ? bq[i] : ((i < 2048) ? bk[i - 1024] : bv[i - 2048]);
    }
}

// ---------------------------------------------------------------- fused QKV GEMM + bias + RoPE + V-transpose
// C = X @ Wqkv^T + bqkv. Q/K cols -> rope -> Qb/Kb (bh, s, d); V cols ->
// written TRANSPOSED directly to Vt (bh, d, s). Q additionally scaled by
// QSC (softmax scale folded out of the attn inner loop).
__global__ __launch_bounds__(256, 3) void gemm_qkv_rope(
        const bf16_t* __restrict__ A, const bf16_t* __restrict__ Bm,
        const float* __restrict__ bias, const float2* __restrict__ tab,
        bf16_t* __restrict__ Qb, bf16_t* __restrict__ Kb, bf16_t* __restrict__ Vt)
{
    __shared__ __attribute__((aligned(16))) bf16_t As[128 * 32];
    __shared__ __attribute__((aligned(16))) bf16_t Bs[128 * 32];
    const int t = threadIdx.x;
    const int lane = t & 63, w = t >> 6;
    const int wm = w >> 1, wn = w & 1;
    const int l15 = lane & 15, l4 = lane >> 4;
    const int xg = l15 & 3;                  // read-side swizzle (= row&3)
    const long rowA0 = (long)blockIdx.x * 128;
    const long rowB0 = (long)blockIdx.y * 128;
    const int K = 1024;

    const f32x4 vz = {0.f, 0.f, 0.f, 0.f};
    f32x4 acc[4][4];
#pragma unroll
    for (int i = 0; i < 4; ++i)
#pragma unroll
        for (int j = 0; j < 4; ++j) acc[i][j] = vz;

    for (int kk = 0; kk < K; kk += 32) {
        __syncthreads();
#pragma unroll
        for (int i = 0; i < 2; ++i) {
            const int cb = i * 256 + w * 64;
            const int c  = cb + lane;
            const int r  = c >> 2;
            const int ko = ((c & 3) ^ (r & 3)) << 3;   // swizzled src chunk
            gload_lds16(A  + (rowA0 + r) * K + kk + ko, As + cb * 8);
            gload_lds16(Bm + (rowB0 + r) * K + kk + ko, Bs + cb * 8);
        }
        __syncthreads();
        bf16x8 af[4], bfr[4];
#pragma unroll
        for (int i = 0; i < 4; ++i)
            af[i] = *(const bf16x8*)(As + (wm * 64 + i * 16 + l15) * 32 + ((l4 ^ xg) * 8));
#pragma unroll
        for (int j = 0; j < 4; ++j)
            bfr[j] = *(const bf16x8*)(Bs + (wn * 64 + j * 16 + l15) * 32 + ((l4 ^ xg) * 8));
#pragma unroll
        for (int i = 0; i < 4; ++i)
#pragma unroll
            for (int j = 0; j < 4; ++j)
                acc[i][j] = __builtin_amdgcn_mfma_f32_16x16x32_bf16(af[i], bfr[j], acc[i][j], 0, 0, 0);
    }

    const long crow0 = rowA0 + wm * 64;
    const int  ccol0 = (int)rowB0 + wn * 64;     // global col in [0,3072), multiple of 64
    const int  part  = blockIdx.y >> 3;          // 0=Q, 1=K, 2=V
    const int  b     = (int)(crow0 >> 11);
    const int  s0    = (int)(crow0 & 2047);      // 64 rows stay in one batch

    if (part == 2) {
        const int h = (ccol0 - 2048) >> 6;       // wave-constant head
#pragma unroll
        for (int j = 0; j < 4; ++j) {
            const int d = j * 16 + l15;
            const float bb = bias[ccol0 + j * 16 + l15];
            bf16_t* dstc = Vt + ((long)(b * HH + h) * DH + d) * SS + s0;
#pragma unroll
            for (int i = 0; i < 4; ++i) {
                bf16x4 pk;
                pk.x = (bf16_t)(acc[i][j][0] + bb);
                pk.y = (bf16_t)(acc[i][j][1] + bb);
                pk.z = (bf16_t)(acc[i][j][2] + bb);
                pk.w = (bf16_t)(acc[i][j][3] + bb);
                *(bf16x4*)(dstc + i * 16 + l4 * 4) = pk;
            }
        }
    } else {
        bf16_t* dst0 = part ? Kb : Qb;
        const float osc = part ? 1.0f : QSC;     // fold softmax scale into Q
        const int h = (ccol0 & 1023) >> 6;       // this wave's 64-col strip = one head
        const int even = !(l15 & 1);
        bf16_t* dsth = dst0 + (long)(b * HH + h) * SS * DH;
        // j-outer: trow/bias hoisted per column; [pr][s] table gives the 4
        // consecutive-s cos/sin pairs per (i,j) as one 32B contiguous read.
#pragma unroll
        for (int j = 0; j < 4; ++j) {
            const int col = ccol0 + j * 16 + l15;
            const float bb = bias[col];
            const int dd = j * 16 + l15;
            const float2* trow = tab + (long)((col >> 1) & 511) * SS;
#pragma unroll
            for (int i = 0; i < 4; ++i) {
                const int sb = s0 + i * 16 + l4 * 4;          // multiple of 4
                const float4 csA = *(const float4*)(trow + sb);      // r=0,1
                const float4 csB = *(const float4*)(trow + sb + 2);  // r=2,3
                const float cc[4] = {csA.x, csA.z, csB.x, csB.z};
                const float sn[4] = {csA.y, csA.w, csB.y, csB.w};
#pragma unroll
                for (int r = 0; r < 4; ++r) {
                    const float val = acc[i][j][r] + bb;
                    const float par = __shfl_xor(val, 1);
                    const float out = even ? (val * cc[r] - par * sn[r])
                                           : fmaf(val, cc[r], par * sn[r]);
                    // pair-store: even lane writes {out_even, out_odd} as b32
                    const float op = __shfl_xor(out, 1);
                    if (even) {
                        union { bf16_t hh[2]; unsigned int u; } cv;
                        cv.hh[0] = (bf16_t)(out * osc); cv.hh[1] = (bf16_t)(op * osc);
                        *(unsigned int*)(dsth + ((long)(sb + r)) * DH + dd) = cv.u;
                    }
                }
            }
        }
    }
}

// ---------------------------------------------------------------- NT GEMM (output projection)
template <int OUT_BF16>
__global__ __launch_bounds__(256, 3) void gemm_bt(
        const bf16_t* __restrict__ A, const bf16_t* __restrict__ Bm,
        const float* __restrict__ bias, void* __restrict__ Cout,
        int M, int N, int K)
{
    __shared__ __attribute__((aligned(16))) bf16_t As[128 * 32];
    __shared__ __attribute__((aligned(16))) bf16_t Bs[128 * 32];
    const int t = threadIdx.x;
    const int lane = t & 63, w = t >> 6;
    const int wm = w >> 1, wn = w & 1;
    const int l15 = lane & 15, l4 = lane >> 4;
    const int xg = l15 & 3;
    const long rowA0 = (long)blockIdx.x * 128;
    const long rowB0 = (long)blockIdx.y * 128;

    const f32x4 vz = {0.f, 0.f, 0.f, 0.f};
    f32x4 acc[4][4];
#pragma unroll
    for (int i = 0; i < 4; ++i)
#pragma unroll
        for (int j = 0; j < 4; ++j) acc[i][j] = vz;

    for (int kk = 0; kk < K; kk += 32) {
        __syncthreads();
#pragma unroll
        for (int i = 0; i < 2; ++i) {
            const int cb = i * 256 + w * 64;
            const int c  = cb + lane;
            const int r  = c >> 2;
            const int ko = ((c & 3) ^ (r & 3)) << 3;   // swizzled src chunk
            gload_lds16(A  + (rowA0 + r) * K + kk + ko, As + cb * 8);
            gload_lds16(Bm + (rowB0 + r) * K + kk + ko, Bs + cb * 8);
        }
        __syncthreads();
        bf16x8 af[4], bfr[4];
#pragma unroll
        for (int i = 0; i < 4; ++i)
            af[i] = *(const bf16x8*)(As + (wm * 64 + i * 16 + l15) * 32 + ((l4 ^ xg) * 8));
#pragma unroll
        for (int j = 0; j < 4; ++j)
            bfr[j] = *(const bf16x8*)(Bs + (wn * 64 + j * 16 + l15) * 32 + ((l4 ^ xg) * 8));
#pragma unroll
        for (int i = 0; i < 4; ++i)
#pragma unroll
            for (int j = 0; j < 4; ++j)
                acc[i][j] = __builtin_amdgcn_mfma_f32_16x16x32_bf16(af[i], bfr[j], acc[i][j], 0, 0, 0);
    }

    const long crow0 = rowA0 + wm * 64;
    const int  ccol0 = (int)rowB0 + wn * 64;
#pragma unroll
    for (int i = 0; i < 4; ++i) {
#pragma unroll
        for (int j = 0; j < 4; ++j) {
            const int col = ccol0 + j * 16 + l15;
            const float bb = bias[col];
#pragma unroll
            for (int r = 0; r < 4; ++r) {
                const long row = crow0 + i * 16 + l4 * 4 + r;
                const float v = acc[i][j][r] + bb;
                if (OUT_BF16) ((bf16_t*)Cout)[row * N + col] = (bf16_t)v;
                else          ((float*)Cout)[row * N + col]  = v;
            }
        }
    }
}

// ---------------------------------------------------------------- flash attention
// R11 structure (measured improvement over R8): R8 loop skeleton
// (single-buffer K/V, Ps in LDS, 128-row q-tile, 2 strips/wave, two
// __syncthreads per kt, compiler-scheduled) + VALU diet:
//  - Q pre-scaled by QSC in GEMM1, bias dropped: p = exp2(sacc) raw.
//  - l_sum via ones-column MFMA (P·1 row sums) on the MFMA pipe; its D-layout
//    row (l4*4+r) matches oacc, so epilogue is invr[r] = 1/lacc[s][r].
//  - bh-major grid (XCD pinning, FETCH 139->33 MB measured).
__global__ __launch_bounds__(256, 4) void attn_kernel(const bf16_t* __restrict__ Qb,
                                                      const bf16_t* __restrict__ Kb,
                                                      const bf16_t* __restrict__ Vt,
                                                      bf16_t* __restrict__ Ob)
{
    __shared__ __attribute__((aligned(16))) bf16_t Ks[64 * 64];   // [key][d], swizzled
    __shared__ __attribute__((aligned(16))) bf16_t Vs[64 * 64];   // [d][key], swizzled
    __shared__ __attribute__((aligned(16))) bf16_t Ps[128 * 72];  // [q][key], pitch 72
    const int t = threadIdx.x, lane = t & 63, w = t >> 6;
    const int l15 = lane & 15, l4 = lane >> 4;
    const int xr = l15 & 7;               // read-side swizzle pattern (= row&7)
    const int bh = blockIdx.x, qt = blockIdx.y;
    const bf16_t* Qbh = Qb + (long)bh * SS * DH;
    const bf16_t* Kbh = Kb + (long)bh * SS * DH;
    const bf16_t* Vbh = Vt + (long)bh * DH * SS;

    const int qbase = qt * 128 + w * 32;
    bf16x8 qf[2][2];
#pragma unroll
    for (int s = 0; s < 2; ++s) {
        const long qrow = qbase + 16 * s + l15;
        qf[s][0] = *(const bf16x8*)(Qbh + qrow * DH + l4 * 8);
        qf[s][1] = *(const bf16x8*)(Qbh + qrow * DH + 32 + l4 * 8);
    }

    bf16x8 ones;
#pragma unroll
    for (int e = 0; e < 8; ++e) ones[e] = (bf16_t)1.0f;

    const f32x4 vz = {0.f, 0.f, 0.f, 0.f};
    f32x4 oacc[2][4];
    f32x4 lacc[2];
#pragma unroll
    for (int s = 0; s < 2; ++s) {
        lacc[s] = vz;
#pragma unroll
        for (int j = 0; j < 4; ++j) oacc[s][j] = vz;
    }

    int srow[2], scc[2];
#pragma unroll
    for (int i = 0; i < 2; ++i) {
        const int L = i * 256 + w * 64 + lane;
        srow[i] = L >> 3;
        scc[i]  = (L & 7) ^ (srow[i] & 7);
    }

    for (int kt = 0; kt < SS / 64; ++kt) {
        __syncthreads();
        const bf16_t* Ksrc = Kbh + (long)kt * 64 * DH;
#pragma unroll
        for (int i = 0; i < 2; ++i) {
            const int cb = i * 256 + w * 64;
            gload_lds16(Ksrc + srow[i] * 64 + scc[i] * 8, Ks + cb * 8);
            gload_lds16(Vbh + (long)srow[i] * SS + kt * 64 + scc[i] * 8, Vs + cb * 8);
        }
        __syncthreads();

        // S^T = K Q^T for both strips; kf shared across strips
        f32x4 sacc[2][4];
#pragma unroll
        for (int s = 0; s < 2; ++s)
#pragma unroll
            for (int j = 0; j < 4; ++j) sacc[s][j] = vz;
#pragma unroll
        for (int j = 0; j < 4; ++j) {
            const int rk = (j * 16 + l15) * 64;
            const bf16x8 kf0 = *(const bf16x8*)(Ks + rk + ((l4 ^ xr) * 8));
            const bf16x8 kf1 = *(const bf16x8*)(Ks + rk + (((4 + l4) ^ xr) * 8));
#pragma unroll
            for (int s = 0; s < 2; ++s) {
                sacc[s][j] = __builtin_amdgcn_mfma_f32_16x16x32_bf16(kf0, qf[s][0], sacc[s][j], 0, 0, 0);
                sacc[s][j] = __builtin_amdgcn_mfma_f32_16x16x32_bf16(kf1, qf[s][1], sacc[s][j], 0, 0, 0);
            }
        }

        // p = exp2(s) (scale folded into Q, bias dropped — softmax invariant)
#pragma unroll
        for (int s = 0; s < 2; ++s) {
#pragma unroll
            for (int j = 0; j < 4; ++j) {
                const float p0 = EXP2F(sacc[s][j][0]);
                const float p1 = EXP2F(sacc[s][j][1]);
                const float p2 = EXP2F(sacc[s][j][2]);
                const float p3 = EXP2F(sacc[s][j][3]);
                bf16x4 pk;
                pk.x = (bf16_t)p0; pk.y = (bf16_t)p1; pk.z = (bf16_t)p2; pk.w = (bf16_t)p3;
                *(bf16x4*)(Ps + (w * 32 + 16 * s + l15) * 72 + j * 16 + l4 * 4) = pk;
            }
        }
        // no __syncthreads(): Ps rows [w*32, w*32+32) are wave-local;
        // in-wave DS ops complete in order.

        bf16x8 pf[2][2];
#pragma unroll
        for (int s = 0; s < 2; ++s) {
            pf[s][0] = *(const bf16x8*)(Ps + (w * 32 + 16 * s + l15) * 72 + l4 * 8);
            pf[s][1] = *(const bf16x8*)(Ps + (w * 32 + 16 * s + l15) * 72 + 32 + l4 * 8);
            // row sums on the MFMA pipe: lacc[s][r] = sum_k P[q=l4*4+r][k]
            lacc[s] = __builtin_amdgcn_mfma_f32_16x16x32_bf16(pf[s][0], ones, lacc[s], 0, 0, 0);
            lacc[s] = __builtin_amdgcn_mfma_f32_16x16x32_bf16(pf[s][1], ones, lacc[s], 0, 0, 0);
        }
#pragma unroll
        for (int j = 0; j < 4; ++j) {
            const int rv = (j * 16 + l15) * 64;
            const bf16x8 vf0 = *(const bf16x8*)(Vs + rv + ((l4 ^ xr) * 8));
            const bf16x8 vf1 = *(const bf16x8*)(Vs + rv + (((4 + l4) ^ xr) * 8));
#pragma unroll
            for (int s = 0; s < 2; ++s) {
                oacc[s][j] = __builtin_amdgcn_mfma_f32_16x16x32_bf16(pf[s][0], vf0, oacc[s][j], 0, 0, 0);
                oacc[s][j] = __builtin_amdgcn_mfma_f32_16x16x32_bf16(pf[s][1], vf1, oacc[s][j], 0, 0, 0);
            }
        }
    }

    const int b = bh >> 4, h = bh & 15;
#pragma unroll
    for (int s = 0; s < 2; ++s) {
        float invr[4];
#pragma unroll
        for (int r = 0; r < 4; ++r)
            invr[r] = 1.0f / lacc[s][r];      // layout matches oacc rows directly
#pragma unroll
        for (int j = 0; j < 4; ++j) {
#pragma unroll
            for (int r = 0; r < 4; ++r) {
                const int row = qbase + 16 * s + l4 * 4 + r;
                const float v = oacc[s][j][r] * invr[r];
                Ob[((long)(b * SS + row)) * DD + h * DH + j * 16 + l15] = (bf16_t)v;
            }
        }
    }
}

// ---------------------------------------------------------------- launch
extern "C" void kernel_launch(void* const* d_in, const int* in_sizes, int n_in,
                              void* d_out, int out_size, void* d_ws, size_t ws_size,
                              hipStream_t stream)
{
    const float* queries = (const float*)d_in[0];
    const float* Wq = (const float*)d_in[1];
    const float* bq = (const float*)d_in[2];
    const float* Wk = (const float*)d_in[3];
    const float* bk = (const float*)d_in[4];
    const float* Wv = (const float*)d_in[5];
    const float* bv = (const float*)d_in[6];
    const float* Wo = (const float*)d_in[7];
    const float* bo = (const float*)d_in[8];

    char* ws = (char*)d_ws;
    size_t off = 0;
    auto alloc = [&](size_t bytes) { size_t o = off; off += (bytes + 255) & ~(size_t)255; return o; };
    bf16_t* Xb   = (bf16_t*)(ws + alloc(8192u * 1024u * 2u));       // 16 MB
    bf16_t* Wqkv = (bf16_t*)(ws + alloc(3072u * 1024u * 2u));       // 6 MB
    bf16_t* Wob  = (bf16_t*)(ws + alloc(1024u * 1024u * 2u));       // 2 MB
    float*  bqkv = (float*) (ws + alloc(3072u * 4u));
    float2* tab  = (float2*)(ws + alloc(2048u * 512u * 8u));        // 8 MB, [pr][s]
    bf16_t* Qb   = (bf16_t*)(ws + alloc(64u * 2048u * 64u * 2u));   // 16 MB
    bf16_t* Kb   = (bf16_t*)(ws + alloc(64u * 2048u * 64u * 2u));   // 16 MB
    bf16_t* Vt   = (bf16_t*)(ws + alloc(64u * 64u * 2048u * 2u));   // 16 MB
    bf16_t* Ob   = Xb;  // alias: Xb is dead after GEMM1

    prep_kernel<<<16396, 256, 0, stream>>>(queries, Wq, Wk, Wv, Wo, bq, bk, bv,
                                           Xb, Wqkv, Wob, bqkv, tab);

    gemm_qkv_rope<<<dim3(64, 24), 256, 0, stream>>>(Xb, Wqkv, bqkv, tab, Qb, Kb, Vt);
    attn_kernel<<<dim3(64, 16), 256, 0, stream>>>(Qb, Kb, Vt, Ob);
    gemm_bt<0><<<dim3(64, 8), 256, 0, stream>>>(Ob, Wob, bo, d_out, 8192, 1024, 1024);
}

// Round 5
// 274.455 us; speedup vs baseline: 1.0573x; 1.0573x over previous
//
#include <hip/hip_runtime.h>
#include <stdint.h>

typedef __bf16 bf16_t;
typedef __bf16 bf16x4 __attribute__((ext_vector_type(4)));
typedef __bf16 bf16x8 __attribute__((ext_vector_type(8)));
typedef float  f32x4  __attribute__((ext_vector_type(4)));

#define BB   4
#define SS   2048
#define DD   1024
#define HH   16
#define DH   64

#if __has_builtin(__builtin_amdgcn_exp2f)
#define EXP2F(x) __builtin_amdgcn_exp2f(x)
#else
#define EXP2F(x) __expf((x) * 0.6931471805599453f)
#endif

// Q pre-scale: 0.125 * log2(e). Folded into Qb at the GEMM1 epilogue (f32
// multiply BEFORE bf16 round -> zero precision cost). Softmax is invariant
// to a constant factor on p, so attn inner loop does p = exp2(s) raw.
#define QSC 0.18033688011112042f

// ---------------------------------------------------------------- helpers
__device__ __forceinline__ void gload_lds16(const void* g, void* l) {
    // dest LDS addr = wave-uniform base + lane*16 (measured m104/m108)
    __builtin_amdgcn_global_load_lds(
        (__attribute__((address_space(1))) void*)(uintptr_t)g,
        (__attribute__((address_space(3))) void*)(uint32_t)(uintptr_t)l,
        16, 0, 0);
}

// ---------------------------------------------------------------- fused prep
// one launch: X fp32->bf16 (8192 blocks), 4 weights fp32->bf16 (4096),
// rope cos/sin table [pr][s] (4096), bias pack (12). grid = 16396.
__global__ __launch_bounds__(256) void prep_kernel(
        const float* __restrict__ queries,
        const float* __restrict__ Wq, const float* __restrict__ Wk,
        const float* __restrict__ Wv, const float* __restrict__ Wo,
        const float* __restrict__ bq, const float* __restrict__ bk,
        const float* __restrict__ bv,
        bf16_t* __restrict__ Xb, bf16_t* __restrict__ Wqkv,
        bf16_t* __restrict__ Wob, float* __restrict__ bqkv,
        float2* __restrict__ tab)
{
    const int bid = blockIdx.x, t = threadIdx.x;
    if (bid < 8192) {                       // X convert: 2097152 float4
        const int i = bid * 256 + t;
        float4 v = ((const float4*)queries)[i];
        bf16x4 o;
        o.x = (bf16_t)v.x; o.y = (bf16_t)v.y; o.z = (bf16_t)v.z; o.w = (bf16_t)v.w;
        ((bf16x4*)Xb)[i] = o;
    } else if (bid < 12288) {               // weights: 1048576 float4
        const int i = (bid - 8192) * 256 + t;
        const int which = i >> 18, p = i & 262143;
        const float* src = (which == 0) ? Wq : (which == 1) ? Wk : (which == 2) ? Wv : Wo;
        bf16_t* dst = (which < 3) ? (Wqkv + (long)which * 1048576) : Wob;
        float4 v = ((const float4*)src)[p];
        bf16x4 o;
        o.x = (bf16_t)v.x; o.y = (bf16_t)v.y; o.z = (bf16_t)v.z; o.w = (bf16_t)v.w;
        ((bf16x4*)dst)[p] = o;
    } else if (bid < 16384) {               // rope table: [pr][s], 512*2048
        const int i = (bid - 12288) * 256 + t;
        const int pr = i >> 11, s = i & 2047;   // pr wave-uniform per block
        float inv = exp2f(-(float)(2 * pr) * 0.012976281620653759f);
        float c, sn;
        sincosf((float)s * inv, &sn, &c);
        tab[i] = make_float2(c, sn);        // tab[pr*2048 + s]
    } else {                                // bias pack: 3072
        const int i = (bid - 16384) * 256 + t;
        if (i < 3072)
            bqkv[i] = (i < 1024) ? bq[i] : ((i < 2048) ? bk[i - 1024] : bv[i - 2048]);
    }
}

// ---------------------------------------------------------------- fused QKV GEMM + bias + RoPE + V-transpose
// R13: BK 32 -> 64. The 2-phase loop's cost is the per-K-step
// vmcnt(0)-drain + 2 barriers (m233: ~72% overhead signature; our counters:
// MfmaUtil 22 / VALU 15 / HBM 15 = all pipes idle). BK=64 halves the
// barrier/drain count and doubles loads-in-flight per drain; ds_read/MFMA
// totals and register live-set unchanged (fragments re-read per 32-K half).
// [128][64] tile row = 128 B -> chunk^(row&7) XOR swizzle (G4/m214) makes
// each b128 read hit all 32 banks uniformly. LDS 32 KB (5 blocks/CU limit).
__global__ __launch_bounds__(256, 3) void gemm_qkv_rope(
        const bf16_t* __restrict__ A, const bf16_t* __restrict__ Bm,
        const float* __restrict__ bias, const float2* __restrict__ tab,
        bf16_t* __restrict__ Qb, bf16_t* __restrict__ Kb, bf16_t* __restrict__ Vt)
{
    __shared__ __attribute__((aligned(16))) bf16_t As[128 * 64];
    __shared__ __attribute__((aligned(16))) bf16_t Bs[128 * 64];
    const int t = threadIdx.x;
    const int lane = t & 63, w = t >> 6;
    const int wm = w >> 1, wn = w & 1;
    const int l15 = lane & 15, l4 = lane >> 4;
    const int xr = l15 & 7;                  // read-side swizzle (= row&7)
    const long rowA0 = (long)blockIdx.x * 128;
    const long rowB0 = (long)blockIdx.y * 128;
    const int K = 1024;

    const f32x4 vz = {0.f, 0.f, 0.f, 0.f};
    f32x4 acc[4][4];
#pragma unroll
    for (int i = 0; i < 4; ++i)
#pragma unroll
        for (int j = 0; j < 4; ++j) acc[i][j] = vz;

    // staging slots: 16B chunk S = r*8 + ch; LDS chunk ch holds global
    // chunk ch^(r&7) (pre-swizzled source, linear DMA dest)
    int srow[4], sko[4];
#pragma unroll
    for (int i = 0; i < 4; ++i) {
        const int c = i * 256 + w * 64 + lane;
        srow[i] = c >> 3;
        sko[i]  = ((c & 7) ^ (srow[i] & 7)) << 3;
    }

    for (int kk = 0; kk < K; kk += 64) {
        __syncthreads();
#pragma unroll
        for (int i = 0; i < 4; ++i) {
            const int cb = i * 256 + w * 64;
            gload_lds16(A  + (rowA0 + srow[i]) * K + kk + sko[i], As + cb * 8);
            gload_lds16(Bm + (rowB0 + srow[i]) * K + kk + sko[i], Bs + cb * 8);
        }
        __syncthreads();
#pragma unroll
        for (int kk2 = 0; kk2 < 2; ++kk2) {
            bf16x8 af[4], bfr[4];
#pragma unroll
            for (int i = 0; i < 4; ++i)
                af[i] = *(const bf16x8*)(As + (wm * 64 + i * 16 + l15) * 64 + ((((kk2 << 2) | l4) ^ xr) * 8));
#pragma unroll
            for (int j = 0; j < 4; ++j)
                bfr[j] = *(const bf16x8*)(Bs + (wn * 64 + j * 16 + l15) * 64 + ((((kk2 << 2) | l4) ^ xr) * 8));
#pragma unroll
            for (int i = 0; i < 4; ++i)
#pragma unroll
                for (int j = 0; j < 4; ++j)
                    acc[i][j] = __builtin_amdgcn_mfma_f32_16x16x32_bf16(af[i], bfr[j], acc[i][j], 0, 0, 0);
        }
    }

    const long crow0 = rowA0 + wm * 64;
    const int  ccol0 = (int)rowB0 + wn * 64;     // global col in [0,3072), multiple of 64
    const int  part  = blockIdx.y >> 3;          // 0=Q, 1=K, 2=V
    const int  b     = (int)(crow0 >> 11);
    const int  s0    = (int)(crow0 & 2047);      // 64 rows stay in one batch

    if (part == 2) {
        const int h = (ccol0 - 2048) >> 6;       // wave-constant head
#pragma unroll
        for (int j = 0; j < 4; ++j) {
            const int d = j * 16 + l15;
            const float bb = bias[ccol0 + j * 16 + l15];
            bf16_t* dstc = Vt + ((long)(b * HH + h) * DH + d) * SS + s0;
#pragma unroll
            for (int i = 0; i < 4; ++i) {
                bf16x4 pk;
                pk.x = (bf16_t)(acc[i][j][0] + bb);
                pk.y = (bf16_t)(acc[i][j][1] + bb);
                pk.z = (bf16_t)(acc[i][j][2] + bb);
                pk.w = (bf16_t)(acc[i][j][3] + bb);
                *(bf16x4*)(dstc + i * 16 + l4 * 4) = pk;
            }
        }
    } else {
        bf16_t* dst0 = part ? Kb : Qb;
        const float osc = part ? 1.0f : QSC;     // fold softmax scale into Q
        const int h = (ccol0 & 1023) >> 6;       // this wave's 64-col strip = one head
        const int even = !(l15 & 1);
        bf16_t* dsth = dst0 + (long)(b * HH + h) * SS * DH;
        // i-outer (write locality: full rows completed before moving on —
        // R12's j-outer cost +12 MB WRITE_SIZE); [pr][s] table keeps the 4
        // consecutive-s cos/sin pairs as two contiguous float4 reads.
#pragma unroll
        for (int i = 0; i < 4; ++i) {
            const int sb = s0 + i * 16 + l4 * 4;          // multiple of 4
#pragma unroll
            for (int j = 0; j < 4; ++j) {
                const int col = ccol0 + j * 16 + l15;
                const float bb = bias[col];
                const int dd = j * 16 + l15;
                const float2* trow = tab + (long)((col >> 1) & 511) * SS;
                const float4 csA = *(const float4*)(trow + sb);      // r=0,1
                const float4 csB = *(const float4*)(trow + sb + 2);  // r=2,3
                const float cc[4] = {csA.x, csA.z, csB.x, csB.z};
                const float sn[4] = {csA.y, csA.w, csB.y, csB.w};
#pragma unroll
                for (int r = 0; r < 4; ++r) {
                    const float val = acc[i][j][r] + bb;
                    const float par = __shfl_xor(val, 1);
                    const float out = even ? (val * cc[r] - par * sn[r])
                                           : fmaf(val, cc[r], par * sn[r]);
                    // pair-store: even lane writes {out_even, out_odd} as b32
                    const float op = __shfl_xor(out, 1);
                    if (even) {
                        union { bf16_t hh[2]; unsigned int u; } cv;
                        cv.hh[0] = (bf16_t)(out * osc); cv.hh[1] = (bf16_t)(op * osc);
                        *(unsigned int*)(dsth + ((long)(sb + r)) * DH + dd) = cv.u;
                    }
                }
            }
        }
    }
}

// ---------------------------------------------------------------- NT GEMM (output projection)
// R13: same BK=64 change as gemm_qkv_rope.
template <int OUT_BF16>
__global__ __launch_bounds__(256, 3) void gemm_bt(
        const bf16_t* __restrict__ A, const bf16_t* __restrict__ Bm,
        const float* __restrict__ bias, void* __restrict__ Cout,
        int M, int N, int K)
{
    __shared__ __attribute__((aligned(16))) bf16_t As[128 * 64];
    __shared__ __attribute__((aligned(16))) bf16_t Bs[128 * 64];
    const int t = threadIdx.x;
    const int lane = t & 63, w = t >> 6;
    const int wm = w >> 1, wn = w & 1;
    const int l15 = lane & 15, l4 = lane >> 4;
    const int xr = l15 & 7;
    const long rowA0 = (long)blockIdx.x * 128;
    const long rowB0 = (long)blockIdx.y * 128;

    const f32x4 vz = {0.f, 0.f, 0.f, 0.f};
    f32x4 acc[4][4];
#pragma unroll
    for (int i = 0; i < 4; ++i)
#pragma unroll
        for (int j = 0; j < 4; ++j) acc[i][j] = vz;

    int srow[4], sko[4];
#pragma unroll
    for (int i = 0; i < 4; ++i) {
        const int c = i * 256 + w * 64 + lane;
        srow[i] = c >> 3;
        sko[i]  = ((c & 7) ^ (srow[i] & 7)) << 3;
    }

    for (int kk = 0; kk < K; kk += 64) {
        __syncthreads();
#pragma unroll
        for (int i = 0; i < 4; ++i) {
            const int cb = i * 256 + w * 64;
            gload_lds16(A  + (rowA0 + srow[i]) * K + kk + sko[i], As + cb * 8);
            gload_lds16(Bm + (rowB0 + srow[i]) * K + kk + sko[i], Bs + cb * 8);
        }
        __syncthreads();
#pragma unroll
        for (int kk2 = 0; kk2 < 2; ++kk2) {
            bf16x8 af[4], bfr[4];
#pragma unroll
            for (int i = 0; i < 4; ++i)
                af[i] = *(const bf16x8*)(As + (wm * 64 + i * 16 + l15) * 64 + ((((kk2 << 2) | l4) ^ xr) * 8));
#pragma unroll
            for (int j = 0; j < 4; ++j)
                bfr[j] = *(const bf16x8*)(Bs + (wn * 64 + j * 16 + l15) * 64 + ((((kk2 << 2) | l4) ^ xr) * 8));
#pragma unroll
            for (int i = 0; i < 4; ++i)
#pragma unroll
                for (int j = 0; j < 4; ++j)
                    acc[i][j] = __builtin_amdgcn_mfma_f32_16x16x32_bf16(af[i], bfr[j], acc[i][j], 0, 0, 0);
        }
    }

    const long crow0 = rowA0 + wm * 64;
    const int  ccol0 = (int)rowB0 + wn * 64;
#pragma unroll
    for (int i = 0; i < 4; ++i) {
#pragma unroll
        for (int j = 0; j < 4; ++j) {
            const int col = ccol0 + j * 16 + l15;
            const float bb = bias[col];
#pragma unroll
            for (int r = 0; r < 4; ++r) {
                const long row = crow0 + i * 16 + l4 * 4 + r;
                const float v = acc[i][j][r] + bb;
                if (OUT_BF16) ((bf16_t*)Cout)[row * N + col] = (bf16_t)v;
                else          ((float*)Cout)[row * N + col]  = v;
            }
        }
    }
}

// ---------------------------------------------------------------- flash attention
// R11 structure (measured best): R8 loop skeleton (single-buffer K/V, Ps in
// LDS, 128-row q-tile, 2 strips/wave, two __syncthreads per kt) + VALU diet:
//  - Q pre-scaled by QSC in GEMM1: p = exp2(sacc) raw.
//  - l_sum via ones-column MFMA (P·1 row sums); D-layout row matches oacc,
//    epilogue is invr[r] = 1/lacc[s][r].
//  - bh-major grid (XCD pinning, FETCH 139->33 MB measured).
__global__ __launch_bounds__(256, 4) void attn_kernel(const bf16_t* __restrict__ Qb,
                                                      const bf16_t* __restrict__ Kb,
                                                      const bf16_t* __restrict__ Vt,
                                                      bf16_t* __restrict__ Ob)
{
    __shared__ __attribute__((aligned(16))) bf16_t Ks[64 * 64];   // [key][d], swizzled
    __shared__ __attribute__((aligned(16))) bf16_t Vs[64 * 64];   // [d][key], swizzled
    __shared__ __attribute__((aligned(16))) bf16_t Ps[128 * 72];  // [q][key], pitch 72
    const int t = threadIdx.x, lane = t & 63, w = t >> 6;
    const int l15 = lane & 15, l4 = lane >> 4;
    const int xr = l15 & 7;               // read-side swizzle pattern (= row&7)
    const int bh = blockIdx.x, qt = blockIdx.y;
    const bf16_t* Qbh = Qb + (long)bh * SS * DH;
    const bf16_t* Kbh = Kb + (long)bh * SS * DH;
    const bf16_t* Vbh = Vt + (long)bh * DH * SS;

    const int qbase = qt * 128 + w * 32;
    bf16x8 qf[2][2];
#pragma unroll
    for (int s = 0; s < 2; ++s) {
        const long qrow = qbase + 16 * s + l15;
        qf[s][0] = *(const bf16x8*)(Qbh + qrow * DH + l4 * 8);
        qf[s][1] = *(const bf16x8*)(Qbh + qrow * DH + 32 + l4 * 8);
    }

    bf16x8 ones;
#pragma unroll
    for (int e = 0; e < 8; ++e) ones[e] = (bf16_t)1.0f;

    const f32x4 vz = {0.f, 0.f, 0.f, 0.f};
    f32x4 oacc[2][4];
    f32x4 lacc[2];
#pragma unroll
    for (int s = 0; s < 2; ++s) {
        lacc[s] = vz;
#pragma unroll
        for (int j = 0; j < 4; ++j) oacc[s][j] = vz;
    }

    int srow[2], scc[2];
#pragma unroll
    for (int i = 0; i < 2; ++i) {
        const int L = i * 256 + w * 64 + lane;
        srow[i] = L >> 3;
        scc[i]  = (L & 7) ^ (srow[i] & 7);
    }

    for (int kt = 0; kt < SS / 64; ++kt) {
        __syncthreads();
        const bf16_t* Ksrc = Kbh + (long)kt * 64 * DH;
#pragma unroll
        for (int i = 0; i < 2; ++i) {
            const int cb = i * 256 + w * 64;
            gload_lds16(Ksrc + srow[i] * 64 + scc[i] * 8, Ks + cb * 8);
            gload_lds16(Vbh + (long)srow[i] * SS + kt * 64 + scc[i] * 8, Vs + cb * 8);
        }
        __syncthreads();

        // S^T = K Q^T for both strips; kf shared across strips
        f32x4 sacc[2][4];
#pragma unroll
        for (int s = 0; s < 2; ++s)
#pragma unroll
            for (int j = 0; j < 4; ++j) sacc[s][j] = vz;
#pragma unroll
        for (int j = 0; j < 4; ++j) {
            const int rk = (j * 16 + l15) * 64;
            const bf16x8 kf0 = *(const bf16x8*)(Ks + rk + ((l4 ^ xr) * 8));
            const bf16x8 kf1 = *(const bf16x8*)(Ks + rk + (((4 + l4) ^ xr) * 8));
#pragma unroll
            for (int s = 0; s < 2; ++s) {
                sacc[s][j] = __builtin_amdgcn_mfma_f32_16x16x32_bf16(kf0, qf[s][0], sacc[s][j], 0, 0, 0);
                sacc[s][j] = __builtin_amdgcn_mfma_f32_16x16x32_bf16(kf1, qf[s][1], sacc[s][j], 0, 0, 0);
            }
        }

        // p = exp2(s) (scale folded into Q, bias dropped — softmax invariant)
#pragma unroll
        for (int s = 0; s < 2; ++s) {
#pragma unroll
            for (int j = 0; j < 4; ++j) {
                const float p0 = EXP2F(sacc[s][j][0]);
                const float p1 = EXP2F(sacc[s][j][1]);
                const float p2 = EXP2F(sacc[s][j][2]);
                const float p3 = EXP2F(sacc[s][j][3]);
                bf16x4 pk;
                pk.x = (bf16_t)p0; pk.y = (bf16_t)p1; pk.z = (bf16_t)p2; pk.w = (bf16_t)p3;
                *(bf16x4*)(Ps + (w * 32 + 16 * s + l15) * 72 + j * 16 + l4 * 4) = pk;
            }
        }
        // no __syncthreads(): Ps rows [w*32, w*32+32) are wave-local;
        // in-wave DS ops complete in order.

        bf16x8 pf[2][2];
#pragma unroll
        for (int s = 0; s < 2; ++s) {
            pf[s][0] = *(const bf16x8*)(Ps + (w * 32 + 16 * s + l15) * 72 + l4 * 8);
            pf[s][1] = *(const bf16x8*)(Ps + (w * 32 + 16 * s + l15) * 72 + 32 + l4 * 8);
            // row sums on the MFMA pipe: lacc[s][r] = sum_k P[q=l4*4+r][k]
            lacc[s] = __builtin_amdgcn_mfma_f32_16x16x32_bf16(pf[s][0], ones, lacc[s], 0, 0, 0);
            lacc[s] = __builtin_amdgcn_mfma_f32_16x16x32_bf16(pf[s][1], ones, lacc[s], 0, 0, 0);
        }
#pragma unroll
        for (int j = 0; j < 4; ++j) {
            const int rv = (j * 16 + l15) * 64;
            const bf16x8 vf0 = *(const bf16x8*)(Vs + rv + ((l4 ^ xr) * 8));
            const bf16x8 vf1 = *(const bf16x8*)(Vs + rv + (((4 + l4) ^ xr) * 8));
#pragma unroll
            for (int s = 0; s < 2; ++s) {
                oacc[s][j] = __builtin_amdgcn_mfma_f32_16x16x32_bf16(pf[s][0], vf0, oacc[s][j], 0, 0, 0);
                oacc[s][j] = __builtin_amdgcn_mfma_f32_16x16x32_bf16(pf[s][1], vf1, oacc[s][j], 0, 0, 0);
            }
        }
    }

    const int b = bh >> 4, h = bh & 15;
#pragma unroll
    for (int s = 0; s < 2; ++s) {
        float invr[4];
#pragma unroll
        for (int r = 0; r < 4; ++r)
            invr[r] = 1.0f / lacc[s][r];      // layout matches oacc rows directly
#pragma unroll
        for (int j = 0; j < 4; ++j) {
#pragma unroll
            for (int r = 0; r < 4; ++r) {
                const int row = qbase + 16 * s + l4 * 4 + r;
                const float v = oacc[s][j][r] * invr[r];
                Ob[((long)(b * SS + row)) * DD + h * DH + j * 16 + l15] = (bf16_t)v;
            }
        }
    }
}

// ---------------------------------------------------------------- launch
extern "C" void kernel_launch(void* const* d_in, const int* in_sizes, int n_in,
                              void* d_out, int out_size, void* d_ws, size_t ws_size,
                              hipStream_t stream)
{
    const float* queries = (const float*)d_in[0];
    const float* Wq = (const float*)d_in[1];
    const float* bq = (const float*)d_in[2];
    const float* Wk = (const float*)d_in[3];
    const float* bk = (const float*)d_in[4];
    const float* Wv = (const float*)d_in[5];
    const float* bv = (const float*)d_in[6];
    const float* Wo = (const float*)d_in[7];
    const float* bo = (const float*)d_in[8];

    char* ws = (char*)d_ws;
    size_t off = 0;
    auto alloc = [&](size_t bytes) { size_t o = off; off += (bytes + 255) & ~(size_t)255; return o; };
    bf16_t* Xb   = (bf16_t*)(ws + alloc(8192u * 1024u * 2u));       // 16 MB
    bf16_t* Wqkv = (bf16_t*)(ws + alloc(3072u * 1024u * 2u));       // 6 MB
    bf16_t* Wob  = (bf16_t*)(ws + alloc(1024u * 1024u * 2u));       // 2 MB
    float*  bqkv = (float*) (ws + alloc(3072u * 4u));
    float2* tab  = (float2*)(ws + alloc(2048u * 512u * 8u));        // 8 MB, [pr][s]
    bf16_t* Qb   = (bf16_t*)(ws + alloc(64u * 2048u * 64u * 2u));   // 16 MB
    bf16_t* Kb   = (bf16_t*)(ws + alloc(64u * 2048u * 64u * 2u));   // 16 MB
    bf16_t* Vt   = (bf16_t*)(ws + alloc(64u * 64u * 2048u * 2u));   // 16 MB
    bf16_t* Ob   = Xb;  // alias: Xb is dead after GEMM1

    prep_kernel<<<16396, 256, 0, stream>>>(queries, Wq, Wk, Wv, Wo, bq, bk, bv,
                                           Xb, Wqkv, Wob, bqkv, tab);

    gemm_qkv_rope<<<dim3(64, 24), 256, 0, stream>>>(Xb, Wqkv, bqkv, tab, Qb, Kb, Vt);
    attn_kernel<<<dim3(64, 16), 256, 0, stream>>>(Qb, Kb, Vt, Ob);
    gemm_bt<0><<<dim3(64, 8), 256, 0, stream>>>(Ob, Wob, bo, d_out, 8192, 1024, 1024);
}

// Round 6
// 259.341 us; speedup vs baseline: 1.1189x; 1.0583x over previous
//
#include <hip/hip_runtime.h>
#include <stdint.h>

typedef __bf16 bf16_t;
typedef __bf16 bf16x4 __attribute__((ext_vector_type(4)));
typedef __bf16 bf16x8 __attribute__((ext_vector_type(8)));
typedef float  f32x4  __attribute__((ext_vector_type(4)));

#define BB   4
#define SS   2048
#define DD   1024
#define HH   16
#define DH   64

#if __has_builtin(__builtin_amdgcn_exp2f)
#define EXP2F(x) __builtin_amdgcn_exp2f(x)
#else
#define EXP2F(x) __expf((x) * 0.6931471805599453f)
#endif

// Q pre-scale: 0.125 * log2(e). Folded into Qb at the GEMM1 epilogue (f32
// multiply BEFORE bf16 round -> zero precision cost). Softmax is invariant
// to a constant factor on p, so attn inner loop does p = exp2(s) raw.
#define QSC 0.18033688011112042f

// ---------------------------------------------------------------- helpers
__device__ __forceinline__ void gload_lds16(const void* g, void* l) {
    // dest LDS addr = wave-uniform base + lane*16 (measured m104/m108)
    __builtin_amdgcn_global_load_lds(
        (__attribute__((address_space(1))) void*)(uintptr_t)g,
        (__attribute__((address_space(3))) void*)(uint32_t)(uintptr_t)l,
        16, 0, 0);
}

// ---------------------------------------------------------------- fused prep
// one launch: X fp32->bf16 (8192 blocks), 4 weights fp32->bf16 (4096),
// rope cos/sin table [pr][s] (4096), bias pack (12). grid = 16396.
__global__ __launch_bounds__(256) void prep_kernel(
        const float* __restrict__ queries,
        const float* __restrict__ Wq, const float* __restrict__ Wk,
        const float* __restrict__ Wv, const float* __restrict__ Wo,
        const float* __restrict__ bq, const float* __restrict__ bk,
        const float* __restrict__ bv,
        bf16_t* __restrict__ Xb, bf16_t* __restrict__ Wqkv,
        bf16_t* __restrict__ Wob, float* __restrict__ bqkv,
        float2* __restrict__ tab)
{
    const int bid = blockIdx.x, t = threadIdx.x;
    if (bid < 8192) {                       // X convert: 2097152 float4
        const int i = bid * 256 + t;
        float4 v = ((const float4*)queries)[i];
        bf16x4 o;
        o.x = (bf16_t)v.x; o.y = (bf16_t)v.y; o.z = (bf16_t)v.z; o.w = (bf16_t)v.w;
        ((bf16x4*)Xb)[i] = o;
    } else if (bid < 12288) {               // weights: 1048576 float4
        const int i = (bid - 8192) * 256 + t;
        const int which = i >> 18, p = i & 262143;
        const float* src = (which == 0) ? Wq : (which == 1) ? Wk : (which == 2) ? Wv : Wo;
        bf16_t* dst = (which < 3) ? (Wqkv + (long)which * 1048576) : Wob;
        float4 v = ((const float4*)src)[p];
        bf16x4 o;
        o.x = (bf16_t)v.x; o.y = (bf16_t)v.y; o.z = (bf16_t)v.z; o.w = (bf16_t)v.w;
        ((bf16x4*)dst)[p] = o;
    } else if (bid < 16384) {               // rope table: [pr][s], 512*2048
        const int i = (bid - 12288) * 256 + t;
        const int pr = i >> 11, s = i & 2047;   // pr wave-uniform per block
        float inv = exp2f(-(float)(2 * pr) * 0.012976281620653759f);
        float c, sn;
        sincosf((float)s * inv, &sn, &c);
        tab[i] = make_float2(c, sn);        // tab[pr*2048 + s]
    } else {                                // bias pack: 3072
        const int i = (bid - 16384) * 256 + t;
        if (i < 3072)
            bqkv[i] = (i < 1024) ? bq[i] : ((i < 2048) ? bk[i - 1024] : bv[i - 2048]);
    }
}

// ---------------------------------------------------------------- fused QKV GEMM + bias + RoPE + V-transpose
// R13 (measured win): BK=64 — halves the per-K-step vmcnt(0)-drain + barrier
// count vs BK=32; ds_read/MFMA totals unchanged. chunk^(row&7) XOR swizzle.
__global__ __launch_bounds__(256, 3) void gemm_qkv_rope(
        const bf16_t* __restrict__ A, const bf16_t* __restrict__ Bm,
        const float* __restrict__ bias, const float2* __restrict__ tab,
        bf16_t* __restrict__ Qb, bf16_t* __restrict__ Kb, bf16_t* __restrict__ Vt)
{
    __shared__ __attribute__((aligned(16))) bf16_t As[128 * 64];
    __shared__ __attribute__((aligned(16))) bf16_t Bs[128 * 64];
    const int t = threadIdx.x;
    const int lane = t & 63, w = t >> 6;
    const int wm = w >> 1, wn = w & 1;
    const int l15 = lane & 15, l4 = lane >> 4;
    const int xr = l15 & 7;                  // read-side swizzle (= row&7)
    const long rowA0 = (long)blockIdx.x * 128;
    const long rowB0 = (long)blockIdx.y * 128;
    const int K = 1024;

    const f32x4 vz = {0.f, 0.f, 0.f, 0.f};
    f32x4 acc[4][4];
#pragma unroll
    for (int i = 0; i < 4; ++i)
#pragma unroll
        for (int j = 0; j < 4; ++j) acc[i][j] = vz;

    // staging slots: 16B chunk S = r*8 + ch; LDS chunk ch holds global
    // chunk ch^(r&7) (pre-swizzled source, linear DMA dest)
    int srow[4], sko[4];
#pragma unroll
    for (int i = 0; i < 4; ++i) {
        const int c = i * 256 + w * 64 + lane;
        srow[i] = c >> 3;
        sko[i]  = ((c & 7) ^ (srow[i] & 7)) << 3;
    }

    for (int kk = 0; kk < K; kk += 64) {
        __syncthreads();
#pragma unroll
        for (int i = 0; i < 4; ++i) {
            const int cb = i * 256 + w * 64;
            gload_lds16(A  + (rowA0 + srow[i]) * K + kk + sko[i], As + cb * 8);
            gload_lds16(Bm + (rowB0 + srow[i]) * K + kk + sko[i], Bs + cb * 8);
        }
        __syncthreads();
#pragma unroll
        for (int kk2 = 0; kk2 < 2; ++kk2) {
            bf16x8 af[4], bfr[4];
#pragma unroll
            for (int i = 0; i < 4; ++i)
                af[i] = *(const bf16x8*)(As + (wm * 64 + i * 16 + l15) * 64 + ((((kk2 << 2) | l4) ^ xr) * 8));
#pragma unroll
            for (int j = 0; j < 4; ++j)
                bfr[j] = *(const bf16x8*)(Bs + (wn * 64 + j * 16 + l15) * 64 + ((((kk2 << 2) | l4) ^ xr) * 8));
#pragma unroll
            for (int i = 0; i < 4; ++i)
#pragma unroll
                for (int j = 0; j < 4; ++j)
                    acc[i][j] = __builtin_amdgcn_mfma_f32_16x16x32_bf16(af[i], bfr[j], acc[i][j], 0, 0, 0);
        }
    }

    const long crow0 = rowA0 + wm * 64;
    const int  ccol0 = (int)rowB0 + wn * 64;     // global col in [0,3072), multiple of 64
    const int  part  = blockIdx.y >> 3;          // 0=Q, 1=K, 2=V
    const int  b     = (int)(crow0 >> 11);
    const int  s0    = (int)(crow0 & 2047);      // 64 rows stay in one batch

    if (part == 2) {
        const int h = (ccol0 - 2048) >> 6;       // wave-constant head
#pragma unroll
        for (int j = 0; j < 4; ++j) {
            const int d = j * 16 + l15;
            const float bb = bias[ccol0 + j * 16 + l15];
            bf16_t* dstc = Vt + ((long)(b * HH + h) * DH + d) * SS + s0;
#pragma unroll
            for (int i = 0; i < 4; ++i) {
                bf16x4 pk;
                pk.x = (bf16_t)(acc[i][j][0] + bb);
                pk.y = (bf16_t)(acc[i][j][1] + bb);
                pk.z = (bf16_t)(acc[i][j][2] + bb);
                pk.w = (bf16_t)(acc[i][j][3] + bb);
                *(bf16x4*)(dstc + i * 16 + l4 * 4) = pk;
            }
        }
    } else {
        bf16_t* dst0 = part ? Kb : Qb;
        const float osc = part ? 1.0f : QSC;     // fold softmax scale into Q
        const int h = (ccol0 & 1023) >> 6;       // this wave's 64-col strip = one head
        const int even = !(l15 & 1);
        bf16_t* dsth = dst0 + (long)(b * HH + h) * SS * DH;
        // i-outer (write locality); [pr][s] table: 4 consecutive-s cos/sin
        // pairs per (i,j) = two contiguous float4 reads.
#pragma unroll
        for (int i = 0; i < 4; ++i) {
            const int sb = s0 + i * 16 + l4 * 4;          // multiple of 4
#pragma unroll
            for (int j = 0; j < 4; ++j) {
                const int col = ccol0 + j * 16 + l15;
                const float bb = bias[col];
                const int dd = j * 16 + l15;
                const float2* trow = tab + (long)((col >> 1) & 511) * SS;
                const float4 csA = *(const float4*)(trow + sb);      // r=0,1
                const float4 csB = *(const float4*)(trow + sb + 2);  // r=2,3
                const float cc[4] = {csA.x, csA.z, csB.x, csB.z};
                const float sn[4] = {csA.y, csA.w, csB.y, csB.w};
#pragma unroll
                for (int r = 0; r < 4; ++r) {
                    const float val = acc[i][j][r] + bb;
                    const float par = __shfl_xor(val, 1);
                    const float out = even ? (val * cc[r] - par * sn[r])
                                           : fmaf(val, cc[r], par * sn[r]);
                    // pair-store: even lane writes {out_even, out_odd} as b32
                    const float op = __shfl_xor(out, 1);
                    if (even) {
                        union { bf16_t hh[2]; unsigned int u; } cv;
                        cv.hh[0] = (bf16_t)(out * osc); cv.hh[1] = (bf16_t)(op * osc);
                        *(unsigned int*)(dsth + ((long)(sb + r)) * DH + dd) = cv.u;
                    }
                }
            }
        }
    }
}

// ---------------------------------------------------------------- NT GEMM (output projection)
// R13: BK=64, same as gemm_qkv_rope.
template <int OUT_BF16>
__global__ __launch_bounds__(256, 3) void gemm_bt(
        const bf16_t* __restrict__ A, const bf16_t* __restrict__ Bm,
        const float* __restrict__ bias, void* __restrict__ Cout,
        int M, int N, int K)
{
    __shared__ __attribute__((aligned(16))) bf16_t As[128 * 64];
    __shared__ __attribute__((aligned(16))) bf16_t Bs[128 * 64];
    const int t = threadIdx.x;
    const int lane = t & 63, w = t >> 6;
    const int wm = w >> 1, wn = w & 1;
    const int l15 = lane & 15, l4 = lane >> 4;
    const int xr = l15 & 7;
    const long rowA0 = (long)blockIdx.x * 128;
    const long rowB0 = (long)blockIdx.y * 128;

    const f32x4 vz = {0.f, 0.f, 0.f, 0.f};
    f32x4 acc[4][4];
#pragma unroll
    for (int i = 0; i < 4; ++i)
#pragma unroll
        for (int j = 0; j < 4; ++j) acc[i][j] = vz;

    int srow[4], sko[4];
#pragma unroll
    for (int i = 0; i < 4; ++i) {
        const int c = i * 256 + w * 64 + lane;
        srow[i] = c >> 3;
        sko[i]  = ((c & 7) ^ (srow[i] & 7)) << 3;
    }

    for (int kk = 0; kk < K; kk += 64) {
        __syncthreads();
#pragma unroll
        for (int i = 0; i < 4; ++i) {
            const int cb = i * 256 + w * 64;
            gload_lds16(A  + (rowA0 + srow[i]) * K + kk + sko[i], As + cb * 8);
            gload_lds16(Bm + (rowB0 + srow[i]) * K + kk + sko[i], Bs + cb * 8);
        }
        __syncthreads();
#pragma unroll
        for (int kk2 = 0; kk2 < 2; ++kk2) {
            bf16x8 af[4], bfr[4];
#pragma unroll
            for (int i = 0; i < 4; ++i)
                af[i] = *(const bf16x8*)(As + (wm * 64 + i * 16 + l15) * 64 + ((((kk2 << 2) | l4) ^ xr) * 8));
#pragma unroll
            for (int j = 0; j < 4; ++j)
                bfr[j] = *(const bf16x8*)(Bs + (wn * 64 + j * 16 + l15) * 64 + ((((kk2 << 2) | l4) ^ xr) * 8));
#pragma unroll
            for (int i = 0; i < 4; ++i)
#pragma unroll
                for (int j = 0; j < 4; ++j)
                    acc[i][j] = __builtin_amdgcn_mfma_f32_16x16x32_bf16(af[i], bfr[j], acc[i][j], 0, 0, 0);
        }
    }

    const long crow0 = rowA0 + wm * 64;
    const int  ccol0 = (int)rowB0 + wn * 64;
#pragma unroll
    for (int i = 0; i < 4; ++i) {
#pragma unroll
        for (int j = 0; j < 4; ++j) {
            const int col = ccol0 + j * 16 + l15;
            const float bb = bias[col];
#pragma unroll
            for (int r = 0; r < 4; ++r) {
                const long row = crow0 + i * 16 + l4 * 4 + r;
                const float v = acc[i][j][r] + bb;
                if (OUT_BF16) ((bf16_t*)Cout)[row * N + col] = (bf16_t)v;
                else          ((float*)Cout)[row * N + col]  = v;
            }
        }
    }
}

// ---------------------------------------------------------------- flash attention
// R14: 8-wave / 512-thread block owning 256 q-rows (same R11 per-wave body:
// 2 strips, single-buffer K/V, Ps in LDS, exp2-diet, ones-MFMA l_sum).
// Rationale (R9/R13 amortization lever, applied without an occupancy trade):
// each staged 64-key K/V tile now feeds 8 waves instead of 4 -> staging
// bytes, VMEM issue and DS-write pressure per output HALVE; grid 512 blocks
// = exactly 2 blocks/CU x 8 waves = 16 waves/CU (same occupancy as R13's
// 4x4). Q fetch per bh also halves. LDS 8+8+36 KB = 52 KB.
__global__ __launch_bounds__(512, 4) void attn_kernel(const bf16_t* __restrict__ Qb,
                                                      const bf16_t* __restrict__ Kb,
                                                      const bf16_t* __restrict__ Vt,
                                                      bf16_t* __restrict__ Ob)
{
    __shared__ __attribute__((aligned(16))) bf16_t Ks[64 * 64];   // [key][d], swizzled
    __shared__ __attribute__((aligned(16))) bf16_t Vs[64 * 64];   // [d][key], swizzled
    __shared__ __attribute__((aligned(16))) bf16_t Ps[256 * 72];  // [q][key], pitch 72
    const int t = threadIdx.x, lane = t & 63, w = t >> 6;   // w in [0,8)
    const int l15 = lane & 15, l4 = lane >> 4;
    const int xr = l15 & 7;               // read-side swizzle pattern (= row&7)
    const int bh = blockIdx.x, qt = blockIdx.y;
    const bf16_t* Qbh = Qb + (long)bh * SS * DH;
    const bf16_t* Kbh = Kb + (long)bh * SS * DH;
    const bf16_t* Vbh = Vt + (long)bh * DH * SS;

    const int qbase = qt * 256 + w * 32;  // this wave's 32 q rows (2 strips)
    bf16x8 qf[2][2];
#pragma unroll
    for (int s = 0; s < 2; ++s) {
        const long qrow = qbase + 16 * s + l15;
        qf[s][0] = *(const bf16x8*)(Qbh + qrow * DH + l4 * 8);
        qf[s][1] = *(const bf16x8*)(Qbh + qrow * DH + 32 + l4 * 8);
    }

    bf16x8 ones;
#pragma unroll
    for (int e = 0; e < 8; ++e) ones[e] = (bf16_t)1.0f;

    const f32x4 vz = {0.f, 0.f, 0.f, 0.f};
    f32x4 oacc[2][4];
    f32x4 lacc[2];
#pragma unroll
    for (int s = 0; s < 2; ++s) {
        lacc[s] = vz;
#pragma unroll
        for (int j = 0; j < 4; ++j) oacc[s][j] = vz;
    }

    // staging: 512 threads cover the 512 16B-chunks of each 8KB tile exactly
    const int L    = w * 64 + lane;          // chunk id in [0,512)
    const int srow = L >> 3;                 // tile row (key for Ks, d for Vs)
    const int scc  = (L & 7) ^ (srow & 7);   // pre-swizzled source chunk

    for (int kt = 0; kt < SS / 64; ++kt) {
        __syncthreads();
        const bf16_t* Ksrc = Kbh + (long)kt * 64 * DH;
        gload_lds16(Ksrc + srow * 64 + scc * 8, Ks + L * 8);
        gload_lds16(Vbh + (long)srow * SS + kt * 64 + scc * 8, Vs + L * 8);
        __syncthreads();

        // S^T = K Q^T for both strips; kf shared across strips
        f32x4 sacc[2][4];
#pragma unroll
        for (int s = 0; s < 2; ++s)
#pragma unroll
            for (int j = 0; j < 4; ++j) sacc[s][j] = vz;
#pragma unroll
        for (int j = 0; j < 4; ++j) {
            const int rk = (j * 16 + l15) * 64;
            const bf16x8 kf0 = *(const bf16x8*)(Ks + rk + ((l4 ^ xr) * 8));
            const bf16x8 kf1 = *(const bf16x8*)(Ks + rk + (((4 + l4) ^ xr) * 8));
#pragma unroll
            for (int s = 0; s < 2; ++s) {
                sacc[s][j] = __builtin_amdgcn_mfma_f32_16x16x32_bf16(kf0, qf[s][0], sacc[s][j], 0, 0, 0);
                sacc[s][j] = __builtin_amdgcn_mfma_f32_16x16x32_bf16(kf1, qf[s][1], sacc[s][j], 0, 0, 0);
            }
        }

        // p = exp2(s) (scale folded into Q, bias dropped — softmax invariant)
#pragma unroll
        for (int s = 0; s < 2; ++s) {
#pragma unroll
            for (int j = 0; j < 4; ++j) {
                const float p0 = EXP2F(sacc[s][j][0]);
                const float p1 = EXP2F(sacc[s][j][1]);
                const float p2 = EXP2F(sacc[s][j][2]);
                const float p3 = EXP2F(sacc[s][j][3]);
                bf16x4 pk;
                pk.x = (bf16_t)p0; pk.y = (bf16_t)p1; pk.z = (bf16_t)p2; pk.w = (bf16_t)p3;
                *(bf16x4*)(Ps + (w * 32 + 16 * s + l15) * 72 + j * 16 + l4 * 4) = pk;
            }
        }
        // no __syncthreads(): Ps rows [w*32, w*32+32) are wave-local;
        // in-wave DS ops complete in order.

        bf16x8 pf[2][2];
#pragma unroll
        for (int s = 0; s < 2; ++s) {
            pf[s][0] = *(const bf16x8*)(Ps + (w * 32 + 16 * s + l15) * 72 + l4 * 8);
            pf[s][1] = *(const bf16x8*)(Ps + (w * 32 + 16 * s + l15) * 72 + 32 + l4 * 8);
            // row sums on the MFMA pipe: lacc[s][r] = sum_k P[q=l4*4+r][k]
            lacc[s] = __builtin_amdgcn_mfma_f32_16x16x32_bf16(pf[s][0], ones, lacc[s], 0, 0, 0);
            lacc[s] = __builtin_amdgcn_mfma_f32_16x16x32_bf16(pf[s][1], ones, lacc[s], 0, 0, 0);
        }
#pragma unroll
        for (int j = 0; j < 4; ++j) {
            const int rv = (j * 16 + l15) * 64;
            const bf16x8 vf0 = *(const bf16x8*)(Vs + rv + ((l4 ^ xr) * 8));
            const bf16x8 vf1 = *(const bf16x8*)(Vs + rv + (((4 + l4) ^ xr) * 8));
#pragma unroll
            for (int s = 0; s < 2; ++s) {
                oacc[s][j] = __builtin_amdgcn_mfma_f32_16x16x32_bf16(pf[s][0], vf0, oacc[s][j], 0, 0, 0);
                oacc[s][j] = __builtin_amdgcn_mfma_f32_16x16x32_bf16(pf[s][1], vf1, oacc[s][j], 0, 0, 0);
            }
        }
    }

    const int b = bh >> 4, h = bh & 15;
#pragma unroll
    for (int s = 0; s < 2; ++s) {
        float invr[4];
#pragma unroll
        for (int r = 0; r < 4; ++r)
            invr[r] = 1.0f / lacc[s][r];      // layout matches oacc rows directly
#pragma unroll
        for (int j = 0; j < 4; ++j) {
#pragma unroll
            for (int r = 0; r < 4; ++r) {
                const int row = qbase + 16 * s + l4 * 4 + r;
                const float v = oacc[s][j][r] * invr[r];
                Ob[((long)(b * SS + row)) * DD + h * DH + j * 16 + l15] = (bf16_t)v;
            }
        }
    }
}

// ---------------------------------------------------------------- launch
extern "C" void kernel_launch(void* const* d_in, const int* in_sizes, int n_in,
                              void* d_out, int out_size, void* d_ws, size_t ws_size,
                              hipStream_t stream)
{
    const float* queries = (const float*)d_in[0];
    const float* Wq = (const float*)d_in[1];
    const float* bq = (const float*)d_in[2];
    const float* Wk = (const float*)d_in[3];
    const float* bk = (const float*)d_in[4];
    const float* Wv = (const float*)d_in[5];
    const float* bv = (const float*)d_in[6];
    const float* Wo = (const float*)d_in[7];
    const float* bo = (const float*)d_in[8];

    char* ws = (char*)d_ws;
    size_t off = 0;
    auto alloc = [&](size_t bytes) { size_t o = off; off += (bytes + 255) & ~(size_t)255; return o; };
    bf16_t* Xb   = (bf16_t*)(ws + alloc(8192u * 1024u * 2u));       // 16 MB
    bf16_t* Wqkv = (bf16_t*)(ws + alloc(3072u * 1024u * 2u));       // 6 MB
    bf16_t* Wob  = (bf16_t*)(ws + alloc(1024u * 1024u * 2u));       // 2 MB
    float*  bqkv = (float*) (ws + alloc(3072u * 4u));
    float2* tab  = (float2*)(ws + alloc(2048u * 512u * 8u));        // 8 MB, [pr][s]
    bf16_t* Qb   = (bf16_t*)(ws + alloc(64u * 2048u * 64u * 2u));   // 16 MB
    bf16_t* Kb   = (bf16_t*)(ws + alloc(64u * 2048u * 64u * 2u));   // 16 MB
    bf16_t* Vt   = (bf16_t*)(ws + alloc(64u * 64u * 2048u * 2u));   // 16 MB
    bf16_t* Ob   = Xb;  // alias: Xb is dead after GEMM1

    prep_kernel<<<16396, 256, 0, stream>>>(queries, Wq, Wk, Wv, Wo, bq, bk, bv,
                                           Xb, Wqkv, Wob, bqkv, tab);

    gemm_qkv_rope<<<dim3(64, 24), 256, 0, stream>>>(Xb, Wqkv, bqkv, tab, Qb, Kb, Vt);
    attn_kernel<<<dim3(64, 8), 512, 0, stream>>>(Qb, Kb, Vt, Ob);
    gemm_bt<0><<<dim3(64, 8), 256, 0, stream>>>(Ob, Wob, bo, d_out, 8192, 1024, 1024);
}